// Round 8
// baseline (9968.481 us; speedup 1.0000x reference)
//
#include <hip/hip_runtime.h>

#define Bn 64
#define Sn 512
#define Fn 64
#define Hn 512
#define Un 128
#define Tn 96

typedef __attribute__((ext_vector_type(8))) short bf16x8;
typedef __attribute__((ext_vector_type(4))) float f32x4;
typedef unsigned int u32;

#define MFMA16(a, b, c) __builtin_amdgcn_mfma_f32_16x16x32_bf16(a, b, c, 0, 0, 0)

__device__ __forceinline__ float sigm(float x) { return 1.0f / (1.0f + __expf(-x)); }
__device__ __forceinline__ float tanh_f(float x) {
    x = fminf(fmaxf(x, -15.0f), 15.0f);
    float e = __expf(2.0f * x);
    return (e - 1.0f) / (e + 1.0f);
}
__device__ __forceinline__ short bf16rtn(float f) {
    unsigned u = __float_as_uint(f);
    unsigned r = (u + 0x7FFFu + ((u >> 16) & 1u)) >> 16;
    return (short)r;
}
__device__ __forceinline__ float bf16tof(short s) {
    return __uint_as_float(((unsigned)(unsigned short)s) << 16);
}

// ============================ fused setup kernel ============================
// One launch covers: x hi/lo split+transpose, whh split+perm, wih split+perm,
// bias perm, W1->bf16 transpose, W2->bf16 transpose, state zeroing.
__global__ __launch_bounds__(256)
void k_setup_all(const float* __restrict__ x, const float* __restrict__ whh,
                 const float* __restrict__ wih, const float* __restrict__ bih,
                 const float* __restrict__ bhh, const float* __restrict__ W1,
                 const float* __restrict__ W2,
                 short* __restrict__ xhi, short* __restrict__ xlo,
                 short* __restrict__ whhHi, short* __restrict__ whhLo,
                 short* __restrict__ wihHi, short* __restrict__ wihLo,
                 float* __restrict__ bperm, short* __restrict__ W1Tb,
                 short* __restrict__ W2Tb, float* __restrict__ hz,
                 float* __restrict__ se)
{
    int t = blockIdx.x * 256 + threadIdx.x;
    if (t < 2097152) {                                   // x[b][s][f] -> xT[s][b][f] hi/lo
        int f = t & 63, s = (t >> 6) & 511, b = t >> 15;
        float v = x[t];
        short hi = bf16rtn(v);
        short lo = bf16rtn(v - bf16tof(hi));
        int o = (s * Bn + b) * Fn + f;
        xhi[o] = hi; xlo[o] = lo;
    } else if (t < 3145728) {                            // whh[g*512+j][k] -> row' j*4+g
        t -= 2097152;
        int k = t & 511, r = t >> 9;
        int g = r >> 9, j = r & 511;
        float v = whh[t];
        short hi = bf16rtn(v);
        short lo = bf16rtn(v - bf16tof(hi));
        int o = (j * 4 + g) * 512 + k;
        whhHi[o] = hi; whhLo[o] = lo;
    } else if (t < 3276800) {                            // wih
        t -= 3145728;
        int k = t & 63, r = t >> 6;
        int g = r >> 9, j = r & 511;
        float v = wih[t];
        short hi = bf16rtn(v);
        short lo = bf16rtn(v - bf16tof(hi));
        int o = (j * 4 + g) * 64 + k;
        wihHi[o] = hi; wihLo[o] = lo;
    } else if (t < 3278848) {                            // bias perm
        t -= 3276800;
        int g = t >> 9, j = t & 511;
        bperm[j * 4 + g] = bih[t] + bhh[t];
    } else if (t < 3344384) {                            // W1[u][k] -> W1Tb[k][u] bf16
        t -= 3278848;
        int u = t >> 9, k = t & 511;
        W1Tb[k * Un + u] = bf16rtn(W1[t]);
    } else if (t < 3409920) {                            // W2[u][j] -> W2Tb[j][u] bf16
        t -= 3344384;
        int u = t >> 9, j = t & 511;
        W2Tb[j * Un + u] = bf16rtn(W2[t]);
    } else if (t < 3514368) {                            // zero hHi/hLo/cstG + sumE
        t -= 3409920;
        if (t < 98304) hz[t] = 0.0f;
        else se[t - 98304] = 0.0f;
    }
}

// ============================ encoder: one launch per step (r7, unchanged) ============================
// Grid 256 x 512 threads (8 waves). Block (mt = blk>>1, nt = blk&1): output
// rows mt*16..+16 (rows = j*4+g), batch cols nt*32..+32. Wave (nw = wv&1,
// kw = wv>>1): nw = col-half (16 cols), kw = K-quarter (128). bf16x3 precision.
// C/D layout (verified): col=lane&15, row=(lane>>4)*4+reg -> lane's 4 acc regs
// are gates i,f,g,o of j = mt*4+(lane>>4), batch col = nt*32+nw*16+(lane&15).
__global__ __launch_bounds__(512)
void enc_step3(const short* __restrict__ xhi, const short* __restrict__ xlo,
               const short* __restrict__ whhHi, const short* __restrict__ whhLo,
               const short* __restrict__ wihHi, const short* __restrict__ wihLo,
               const float* __restrict__ bperm,
               const short* __restrict__ hHiP, const short* __restrict__ hLoP,
               short* __restrict__ hHiN, short* __restrict__ hLoN,
               float* __restrict__ cstG, short* __restrict__ encJ, int t)
{
    const int mt = blockIdx.x >> 1, nt = blockIdx.x & 1;
    const int tid = threadIdx.x;
    const int wv = tid >> 6, l = tid & 63;
    const int nw = wv & 1, kw = wv >> 1;
    const int lr = l & 15, lk = l >> 4;
    const int row  = mt * 16 + lr;                   // A-frag row (gate-row)
    const int bcol = nt * 32 + nw * 16 + lr;         // B-frag col (batch)

    f32x4 acc = {0.f, 0.f, 0.f, 0.f};
    // x part on kw<2 (K=64 split 32/32), issued first
    if (kw < 2) {
        int k0 = kw * 32 + lk * 8;
        bf16x8 XBh = *(const bf16x8*)(xhi + ((size_t)t * 64 + bcol) * 64 + k0);
        bf16x8 XBl = *(const bf16x8*)(xlo + ((size_t)t * 64 + bcol) * 64 + k0);
        bf16x8 Ah  = *(const bf16x8*)(wihHi + (size_t)row * 64 + k0);
        bf16x8 Al  = *(const bf16x8*)(wihLo + (size_t)row * 64 + k0);
        acc = MFMA16(Ah, XBh, acc);
        acc = MFMA16(Ah, XBl, acc);
        acc = MFMA16(Al, XBh, acc);
    }
    // recurrent part: this wave's K-quarter (128) in 4 chunks of 32
    #pragma unroll
    for (int c = 0; c < 4; c++) {
        int k0 = kw * 128 + c * 32 + lk * 8;
        bf16x8 Ah = *(const bf16x8*)(whhHi + (size_t)row * 512 + k0);
        bf16x8 Al = *(const bf16x8*)(whhLo + (size_t)row * 512 + k0);
        bf16x8 Bh = *(const bf16x8*)(hHiP + (size_t)bcol * 512 + k0);
        bf16x8 Bl = *(const bf16x8*)(hLoP + (size_t)bcol * 512 + k0);
        acc = MFMA16(Ah, Bh, acc);
        acc = MFMA16(Ah, Bl, acc);
        acc = MFMA16(Al, Bh, acc);
    }
    // K-reduction across kw (4 partials) via LDS
    __shared__ float red[3][2][64][4];
    if (kw) *(f32x4*)(&red[kw - 1][nw][l][0]) = acc;
    __syncthreads();
    if (kw == 0) {
        f32x4 r0 = *(const f32x4*)(&red[0][nw][l][0]);
        f32x4 r1 = *(const f32x4*)(&red[1][nw][l][0]);
        f32x4 r2 = *(const f32x4*)(&red[2][nw][l][0]);
        const int jloc = mt * 4 + lk;
        const f32x4 bias = *(const f32x4*)(bperm + mt * 16 + lk * 4);
        float pi = acc[0] + r0[0] + r1[0] + r2[0] + bias[0];
        float pf = acc[1] + r0[1] + r1[1] + r2[1] + bias[1];
        float pg = acc[2] + r0[2] + r1[2] + r2[2] + bias[2];
        float po = acc[3] + r0[3] + r1[3] + r2[3] + bias[3];
        float ig = sigm(pi), fg = sigm(pf), gg = tanh_f(pg), og = sigm(po);
        float cn = fg * cstG[jloc * Bn + bcol] + ig * gg;
        float hv = og * tanh_f(cn);
        cstG[jloc * Bn + bcol] = cn;
        short hi16 = bf16rtn(hv);
        short lo16 = bf16rtn(hv - bf16tof(hi16));
        hHiN[bcol * 512 + jloc] = hi16;
        hLoN[bcol * 512 + jloc] = lo16;
        encJ[(size_t)jloc * (Sn * Bn) + t * Bn + bcol] = hi16;   // encJ[j][s][b] bf16
    }
}

// ============================ w2_enc GEMM (bf16 in/out) ============================
__global__ __launch_bounds__(256)
void w2enc_k(const short* __restrict__ encJ, const short* __restrict__ W2Tb,
             const float* __restrict__ b2, short* __restrict__ w2eb)
{
    __shared__ float tile[64 * 64];
    const int s = blockIdx.x;
    const int tid = threadIdx.x;
    const int u = tid & 127, bq = tid >> 7;
    float acc[32];
    #pragma unroll
    for (int i = 0; i < 32; i++) acc[i] = 0.f;
    for (int jc = 0; jc < 8; jc++) {
        __syncthreads();
        #pragma unroll
        for (int r = 0; r < 16; r++) {
            int e = r * 256 + tid;
            int jl = e >> 6, b = e & 63;
            tile[e] = bf16tof(encJ[(jc * 64 + jl) * (Sn * Bn) + s * Bn + b]);
        }
        __syncthreads();
        for (int jl = 0; jl < 64; jl++) {
            float wv = bf16tof(W2Tb[(jc * 64 + jl) * Un + u]);
            const float4* trow = (const float4*)&tile[jl * 64 + bq * 32];
            #pragma unroll
            for (int i = 0; i < 8; i++) {
                float4 t4 = trow[i];
                acc[i*4+0] += t4.x * wv; acc[i*4+1] += t4.y * wv;
                acc[i*4+2] += t4.z * wv; acc[i*4+3] += t4.w * wv;
            }
        }
    }
    float bb = b2[u];
    #pragma unroll
    for (int i = 0; i < 32; i++)
        w2eb[(((size_t)(bq * 32 + i)) * Sn + s) * Un + u] = bf16rtn(acc[i] + bb);  // w2eb[b][s][u]
}

// ============================ decoder kernels ============================
// block (b = blk>>2, sc = blk&3). Max-free softmax (|score| <= sum|V| ~ 6):
// e = exp(score); partial sums atomically into sumE. sc==0 also emits out[t-1].
__global__ __launch_bounds__(256)
void dec_attn_k(const float* __restrict__ hdec, const short* __restrict__ encJ,
                const short* __restrict__ W1Tb, const float* __restrict__ b1,
                const float* __restrict__ Vv, const float* __restrict__ bV,
                const short* __restrict__ w2eb, const float* __restrict__ oW,
                const float* __restrict__ ob, float* __restrict__ eT,
                float* __restrict__ sumE, float* __restrict__ out, int t)
{
    __shared__ float hs[512];
    __shared__ float w1h[Un];
    __shared__ float Vs[Un];
    __shared__ float red2[256];
    const int tid = threadIdx.x;
    const int b = blockIdx.x >> 2, sc = blockIdx.x & 3;

    if (t == 0) {   // h_att = encoder final h, from encJ at s = Sn-1
        hs[tid]       = bf16tof(encJ[tid * (Sn * Bn) + (Sn - 1) * Bn + b]);
        hs[tid + 256] = bf16tof(encJ[(tid + 256) * (Sn * Bn) + (Sn - 1) * Bn + b]);
    } else {
        hs[tid]       = hdec[tid * Bn + b];
        hs[tid + 256] = hdec[(tid + 256) * Bn + b];
    }
    if (tid < 128) Vs[tid] = Vv[tid];
    __syncthreads();

    if (sc == 0 && t > 0) {                           // out for previous step
        red2[tid] = oW[tid] * hs[tid] + oW[tid + 256] * hs[tid + 256];
        __syncthreads();
        for (int w = 128; w > 0; w >>= 1) { if (tid < w) red2[tid] += red2[tid + w]; __syncthreads(); }
        if (tid == 0) out[b * Tn + (t - 1)] = red2[0] + ob[0];
        __syncthreads();
    }

    {   // w1h[u] = b1[u] + sum_k W1Tb[k][u] * hs[k]   (bf16 weights)
        const int u = tid & 127, kh = tid >> 7;
        float a = 0.f;
        #pragma unroll 8
        for (int k = 0; k < 256; k++) {
            int kk = kh * 256 + k;
            a += bf16tof(W1Tb[kk * Un + u]) * hs[kk];
        }
        red2[tid] = a;
    }
    __syncthreads();
    if (tid < 128) w1h[tid] = red2[tid] + red2[tid + 128] + b1[tid];
    __syncthreads();

    const int sl = sc * 128 + (tid >> 1), uh = tid & 1;
    const short* r  = w2eb + ((size_t)b * Sn + sl) * Un + uh * 64;
    const float* wp = w1h + uh * 64;
    const float* vp = Vs + uh * 64;
    float s0 = 0.f;
    #pragma unroll
    for (int q = 0; q < 8; q++) {
        bf16x8 v8 = *(const bf16x8*)(r + q * 8);
        #pragma unroll
        for (int e2 = 0; e2 < 8; e2++)
            s0 += vp[q * 8 + e2] * tanh_f(wp[q * 8 + e2] + bf16tof(v8[e2]));
    }
    s0 += __shfl_xor(s0, 1);
    float e = 0.f;
    if (uh == 0) {
        e = __expf(s0 + bV[0]);
        eT[sl * Bn + b] = e;
    }
    __syncthreads();
    red2[tid] = e;
    __syncthreads();
    for (int w = 128; w > 0; w >>= 1) { if (tid < w) red2[tid] += red2[tid + w]; __syncthreads(); }
    if (tid == 0) atomicAdd(&sumE[t * Bn + b], red2[0]);
}

// ctx[j][b] = sum_s e[s][b] * encJ[j][s][b]   (unnormalized; coalesced bf16 reads)
__global__ __launch_bounds__(256)
void dec_ctx_k(const float* __restrict__ eT, const short* __restrict__ encJ,
               float* __restrict__ ctx)
{
    const int tid = threadIdx.x;
    const int j = blockIdx.x;
    const int b = tid & 63, sq = tid >> 6;
    const short* ep = encJ + j * (Sn * Bn) + b;
    float a = 0.f;
    #pragma unroll 8
    for (int s = sq * 128; s < sq * 128 + 128; s++)
        a += eT[s * Bn + b] * bf16tof(ep[s * Bn]);
    __shared__ float red[256];
    red[tid] = a;
    __syncthreads();
    if (sq == 0) ctx[j * Bn + b] = red[b] + red[64 + b] + red[128 + b] + red[192 + b];
}

// decoder LSTM cell v2: 64 blocks x 512 threads, 8 j per block, direct dec_Wih
// reads (row-major [j][513], k-contiguous, wave-uniform -> broadcast). 8-way
// k-split, LDS reduce. Gate pre-act = (W . ctx_unnorm)/sumE + bias.
__global__ __launch_bounds__(512)
void dec_gate2_k(const float* __restrict__ ctx, const float* __restrict__ sumE,
                 const float* __restrict__ dW, const float* __restrict__ dbih,
                 const float* __restrict__ dbhh, float* __restrict__ hdec, int t)
{
    const int tid = threadIdx.x;
    const int b = tid & 63;
    const int kq = __builtin_amdgcn_readfirstlane(tid >> 6);   // wave-uniform
    const int j0 = blockIdx.x * 8;
    float ai[8] = {}, ag[8] = {}, ao[8] = {};
    for (int k = kq * 64; k < kq * 64 + 64; k++) {
        float cv = ctx[k * Bn + b];
        #pragma unroll
        for (int jj = 0; jj < 8; jj++) {
            int j = j0 + jj;
            ai[jj] += dW[(size_t)(j)        * 513 + k] * cv;
            ag[jj] += dW[(size_t)(1024 + j) * 513 + k] * cv;
            ao[jj] += dW[(size_t)(1536 + j) * 513 + k] * cv;
        }
    }
    __shared__ float red[8][24][64];
    #pragma unroll
    for (int jj = 0; jj < 8; jj++) {
        red[kq][jj * 3 + 0][b] = ai[jj];
        red[kq][jj * 3 + 1][b] = ag[jj];
        red[kq][jj * 3 + 2][b] = ao[jj];
    }
    __syncthreads();
    if (kq == 0) {
        float inv = 1.0f / sumE[t * Bn + b];
        #pragma unroll
        for (int jj = 0; jj < 8; jj++) {
            int j = j0 + jj;
            float pi = 0.f, pg = 0.f, po = 0.f;
            #pragma unroll
            for (int q = 0; q < 8; q++) {
                pi += red[q][jj * 3 + 0][b];
                pg += red[q][jj * 3 + 1][b];
                po += red[q][jj * 3 + 2][b];
            }
            pi = pi * inv + dbih[j]          + dbhh[j];
            pg = pg * inv + dbih[2*Hn + j]   + dbhh[2*Hn + j];
            po = po * inv + dbih[3*Hn + j]   + dbhh[3*Hn + j];
            float cc = sigm(pi) * tanh_f(pg);
            float hh = sigm(po) * tanh_f(cc);
            hdec[j * Bn + b] = hh;
        }
    }
}

// final out step (t = Tn-1)
__global__ __launch_bounds__(64)
void dec_out_k(const float* __restrict__ hdec, const float* __restrict__ oW,
               const float* __restrict__ ob, float* __restrict__ out, int t)
{
    const int b = blockIdx.x;
    const int tid = threadIdx.x;
    float a = 0.f;
    #pragma unroll
    for (int q = 0; q < 8; q++) {
        int j = tid + q * 64;
        a += oW[j] * hdec[j * Bn + b];
    }
    for (int off = 32; off; off >>= 1) a += __shfl_down(a, off, 64);
    if (tid == 0) out[b * Tn + t] = a + ob[0];
}

// ============================ host ============================
extern "C" void kernel_launch(void* const* d_in, const int* in_sizes, int n_in,
                              void* d_out, int out_size, void* d_ws, size_t ws_size,
                              hipStream_t stream) {
    const float* x    = (const float*)d_in[0];
    const float* eWih = (const float*)d_in[1];
    const float* eWhh = (const float*)d_in[2];
    const float* ebih = (const float*)d_in[3];
    const float* ebhh = (const float*)d_in[4];
    const float* aW1  = (const float*)d_in[5];
    const float* ab1  = (const float*)d_in[6];
    const float* aW2  = (const float*)d_in[7];
    const float* ab2  = (const float*)d_in[8];
    const float* aV   = (const float*)d_in[9];
    const float* abV  = (const float*)d_in[10];
    const float* dWih = (const float*)d_in[11];
    // d_in[12] = dec_Whh unused (decoder starts from zero state every step)
    const float* dbih = (const float*)d_in[13];
    const float* dbhh = (const float*)d_in[14];
    const float* oW   = (const float*)d_in[15];
    const float* ob   = (const float*)d_in[16];
    float* out = (float*)d_out;

    char* wsb = (char*)d_ws;
    short* xhi    = (short*)(wsb + 0);          // 4,194,304 B
    short* xlo    = (short*)(wsb + 4194304);    // 4,194,304
    short* whhHi  = (short*)(wsb + 8388608);    // 2,097,152
    short* whhLo  = (short*)(wsb + 10485760);   // 2,097,152
    short* wihHi  = (short*)(wsb + 12582912);   // 262,144
    short* wihLo  = (short*)(wsb + 12845056);   // 262,144
    float* bperm  = (float*)(wsb + 13107200);   // 8,192
    short* W2Tb   = (short*)(wsb + 13115392);   // 131,072
    short* W1Tb   = (short*)(wsb + 13246464);   // 131,072 (region reserved 262,144)
    // 13508608..16654336 dead (was WiT/WgT/WoT; dec_gate2 reads dWih directly)
    short* hHi    = (short*)(wsb + 16654336);   // 131,072  [2][32768]
    short* hLo    = (short*)(wsb + 16785408);   // 131,072  [2][32768]
    float* cstG   = (float*)(wsb + 16916480);   // 131,072
    short* encJ   = (short*)(wsb + 17047552);   // 33,554,432  [512][512][64] bf16
    short* w2eb   = (short*)(wsb + 50601984);   // 8,388,608   [64][512][128] bf16
    float* eT     = (float*)(wsb + 58990592);   // 131,072
    float* sumE   = (float*)(wsb + 59121664);   // 24,576
    float* ctx    = (float*)(wsb + 59146240);   // 131,072
    float* hdec   = (float*)(wsb + 59277312);   // 131,072

    // ---- fused setup: 1 node ----
    k_setup_all<<<13728, 256, 0, stream>>>(x, eWhh, eWih, ebih, ebhh, aW1, aW2,
                                           xhi, xlo, whhHi, whhLo, wihHi, wihLo,
                                           bperm, W1Tb, W2Tb, (float*)hHi, sumE);

    // ---- encoder: 512 per-step launches (kernel boundary = grid barrier) ----
    for (int t = 0; t < Sn; t++) {
        const int pr = t & 1, pw = 1 - pr;
        enc_step3<<<256, 512, 0, stream>>>(xhi, xlo, whhHi, whhLo, wihHi, wihLo,
                                           bperm,
                                           hHi + pr * 32768, hLo + pr * 32768,
                                           hHi + pw * 32768, hLo + pw * 32768,
                                           cstG, encJ, t);
    }

    // ---- attention hoist ----
    w2enc_k<<<512, 256, 0, stream>>>(encJ, W2Tb, ab2, w2eb);

    // ---- decoder: 3 kernels per step ----
    for (int t = 0; t < Tn; t++) {
        dec_attn_k<<<256, 256, 0, stream>>>(hdec, encJ, W1Tb, ab1, aV, abV, w2eb,
                                            oW, ob, eT, sumE, out, t);
        dec_ctx_k  <<<512, 256, 0, stream>>>(eT, encJ, ctx);
        dec_gate2_k<<<64,  512, 0, stream>>>(ctx, sumE, dWih, dbih, dbhh, hdec, t);
    }
    dec_out_k<<<64, 64, 0, stream>>>(hdec, oW, ob, out, Tn - 1);
}